// Round 2
// baseline (8383.105 us; speedup 1.0000x reference)
//
#include <hip/hip_runtime.h>
#include <hip/hip_bf16.h>

typedef __hip_bfloat16 bf16;
typedef __attribute__((ext_vector_type(8))) short short8;
typedef __attribute__((ext_vector_type(4))) float f32x4;

#define NB 16
#define PLANE (256*256)

static __device__ __forceinline__ short f2bf(float v){
    __hip_bfloat16 h = __float2bfloat16(v);
    short s; __builtin_memcpy(&s, &h, 2); return s;
}
static __device__ __forceinline__ float bf2f(short s){
    union { unsigned u; float f; } cv;
    cv.u = ((unsigned)(unsigned short)s) << 16; return cv.f;
}

// agent-scope (cross-XCD coherent) accesses — bypass non-coherent per-XCD L2
static __device__ __forceinline__ void  stg_ag(float* p, float v){
    __hip_atomic_store(p, v, __ATOMIC_RELAXED, __HIP_MEMORY_SCOPE_AGENT);
}
static __device__ __forceinline__ float ldg_ag(const float* p){
    return __hip_atomic_load(p, __ATOMIC_RELAXED, __HIP_MEMORY_SCOPE_AGENT);
}

// ---------------- first-layer conv 3x3 (small CIN, VALU), output channel-last bf16 ----------------
template<int CIN, int SPLIT, bool RELU>
__global__ __launch_bounds__(256)
void conv3x3_first(const float* __restrict__ in, const float* __restrict__ in2,
                   const float* __restrict__ wgt, const float* __restrict__ bias,
                   bf16* __restrict__ out)
{
    __shared__ float s_in[CIN][18][18];
    __shared__ float s_w[CIN*9*32];
    const int n  = blockIdx.z;
    const int ty0 = blockIdx.y * 16, tx0 = blockIdx.x * 16;
    const int tid = threadIdx.x;

    for (int idx = tid; idx < CIN*9*32; idx += 256) {
        int co = idx & 31; int rest = idx >> 5;     // rest = ci*9 + k
        s_w[idx] = wgt[(co*CIN + rest/9)*9 + rest%9];
    }
    for (int idx = tid; idx < CIN*18*18; idx += 256) {
        int ci = idx / (18*18); int rr = idx % (18*18);
        int yy = rr / 18, xx = rr % 18;
        int y = ty0 + yy - 1, x = tx0 + xx - 1;
        float v = 0.f;
        if (y >= 0 && y < 256 && x >= 0 && x < 256) {
            if (ci < SPLIT) v = in [((size_t)(n*SPLIT + ci)*256 + y)*256 + x];
            else            v = in2[((size_t)(n*(CIN-SPLIT) + (ci-SPLIT))*256 + y)*256 + x];
        }
        s_in[ci][yy][xx] = v;
    }
    __syncthreads();

    const int ty = tid >> 4, tx = tid & 15;
    float acc[32];
    #pragma unroll
    for (int co = 0; co < 32; co++) acc[co] = bias[co];

    #pragma unroll
    for (int ci = 0; ci < CIN; ci++) {
        #pragma unroll
        for (int ky = 0; ky < 3; ky++)
        #pragma unroll
        for (int kx = 0; kx < 3; kx++) {
            float v = s_in[ci][ty+ky][tx+kx];
            const float* wp = &s_w[(ci*9 + ky*3 + kx)*32];
            #pragma unroll
            for (int co = 0; co < 32; co++) acc[co] = fmaf(v, wp[co], acc[co]);
        }
    }
    const int y = ty0 + ty, x = tx0 + tx;
    size_t base = (((size_t)n*256 + y)*256 + x)*32;
    #pragma unroll
    for (int c = 0; c < 32; c += 8) {
        short8 vv;
        #pragma unroll
        for (int j = 0; j < 8; j++) {
            float v = acc[c+j];
            if (RELU) v = fmaxf(v, 0.f);
            vv[j] = f2bf(v);
        }
        *(short8*)((short*)out + base + c) = vv;
    }
}

// ---------------- weight repack for MFMA convs: [co][ci][tap] f32 -> [tap][co][ci] bf16 ----------------
__global__ __launch_bounds__(256)
void wrepack3(const float* __restrict__ a, const float* __restrict__ b,
              const float* __restrict__ c,
              bf16* __restrict__ oa, bf16* __restrict__ ob, bf16* __restrict__ oc)
{
    int j = blockIdx.x*256 + threadIdx.x;        // 0..27647
    if (j >= 3*9216) return;
    int set = j / 9216, r = j % 9216;
    int tap = r >> 10, rem = r & 1023, co = rem >> 5, ci = rem & 31;
    const float* src = (set == 0) ? a : (set == 1) ? b : c;
    bf16* dst = (set == 0) ? oa : (set == 1) ? ob : oc;
    dst[r] = __float2bfloat16(src[(co*32 + ci)*9 + tap]);
}

// ---------------- heavy conv 3x3 (32->32) via MFMA, channel-last bf16 in/out ----------------
template<bool RELU>
__global__ __launch_bounds__(256)
void conv3x3_mfma(const bf16* __restrict__ in, const bf16* __restrict__ wpk,
                  const float* __restrict__ bias, bf16* __restrict__ out)
{
    const int lane = threadIdx.x & 63, wid = threadIdx.x >> 6;
    const int m = lane & 15, quad = lane >> 4, k0 = quad*8;
    const int n  = blockIdx.z;
    const int x0 = blockIdx.x * 16;
    const int y0 = blockIdx.y * 16 + wid * 4;

    const short* wp = (const short*)wpk;
    short8 bw[2][9];
    #pragma unroll
    for (int g = 0; g < 2; g++)
        #pragma unroll
        for (int tap = 0; tap < 9; tap++)
            bw[g][tap] = *(const short8*)(wp + ((tap*32 + g*16 + m)*32 + k0));
    const float b0 = bias[m], b1 = bias[16 + m];

    const short* inp = (const short*)in + (size_t)n*PLANE*32;
    short* outp = (short*)out + (size_t)n*PLANE*32;

    #pragma unroll
    for (int r = 0; r < 4; r++) {
        const int y = y0 + r;
        f32x4 acc0 = { b0, b0, b0, b0 };
        f32x4 acc1 = { b1, b1, b1, b1 };
        #pragma unroll
        for (int ky = 0; ky < 3; ky++) {
            const int yy = y + ky - 1;
            const bool yok = (unsigned)yy < 256u;
            #pragma unroll
            for (int kx = 0; kx < 3; kx++) {
                const int xp = x0 + kx - 1 + m;
                short8 a = { 0,0,0,0,0,0,0,0 };
                if (yok && (unsigned)xp < 256u)
                    a = *(const short8*)(inp + ((size_t)yy*256 + xp)*32 + k0);
                acc0 = __builtin_amdgcn_mfma_f32_16x16x32_bf16(a, bw[0][ky*3+kx], acc0, 0, 0, 0);
                acc1 = __builtin_amdgcn_mfma_f32_16x16x32_bf16(a, bw[1][ky*3+kx], acc1, 0, 0, 0);
            }
        }
        #pragma unroll
        for (int reg = 0; reg < 4; reg++) {
            int px = x0 + quad*4 + reg;
            size_t idx = ((size_t)y*256 + px)*32;
            float v0 = acc0[reg], v1 = acc1[reg];
            if (RELU) { v0 = fmaxf(v0, 0.f); v1 = fmaxf(v1, 0.f); }
            outp[idx + m]      = f2bf(v0);
            outp[idx + 16 + m] = f2bf(v1);
        }
    }
}

// ---------------- final conv 3x3 (32->1), channel-last input ----------------
__global__ __launch_bounds__(256)
void conv3x3_last(const bf16* __restrict__ in, const float* __restrict__ wgt,
                  const float* __restrict__ bias, float* __restrict__ out)
{
    __shared__ float s_w[288];
    int tid = threadIdx.x;
    for (int i = tid; i < 288; i += 256) s_w[i] = wgt[i];
    __syncthreads();
    int gid = blockIdx.x*256 + tid;
    int n = gid >> 16, h = (gid >> 8) & 255, w = gid & 255;
    const short* inp = (const short*)in + (size_t)n*PLANE*32;
    float sum = bias[0];
    #pragma unroll
    for (int ky = 0; ky < 3; ky++) {
        int yy = h + ky - 1;
        if ((unsigned)yy >= 256u) continue;
        #pragma unroll
        for (int kx = 0; kx < 3; kx++) {
            int xx = w + kx - 1;
            if ((unsigned)xx >= 256u) continue;
            const short8* pp = (const short8*)(inp + ((size_t)yy*256 + xx)*32);
            int tap = ky*3 + kx;
            #pragma unroll
            for (int c4 = 0; c4 < 4; c4++) {
                short8 v = pp[c4];
                #pragma unroll
                for (int j = 0; j < 8; j++)
                    sum = fmaf(bf2f(v[j]), s_w[(c4*8+j)*9 + tap], sum);
            }
        }
    }
    out[gid] = sum;
}

// ---------------- squared neighbor diffs over 32 channels, channel-last ----------------
template<bool ACCUM>
__global__ __launch_bounds__(256)
void dvdh_cl(const bf16* __restrict__ f, float* __restrict__ dv, float* __restrict__ dh)
{
    int bid = blockIdx.x;
    int n = bid >> 8, i = bid & 255, j = threadIdx.x;
    const short8* pc = (const short8*)((const short*)f + (((size_t)n*256 + i)*256 + j)*32);
    const short8* pr = (j < 255) ? pc + 4    : pc;
    const short8* pd = (i < 255) ? pc + 1024 : pc;
    float adv = 0.f, adh = 0.f;
    #pragma unroll
    for (int c4 = 0; c4 < 4; c4++) {
        short8 sc = pc[c4], sr = pr[c4], sd = pd[c4];
        #pragma unroll
        for (int e = 0; e < 8; e++) {
            float fc = bf2f(sc[e]);
            float d1 = bf2f(sr[e]) - fc;
            float d2 = bf2f(sd[e]) - fc;
            adh = fmaf(d1, d1, adh);
            adv = fmaf(d2, d2, adv);
        }
    }
    int o = (n*256 + i)*256 + j;
    if (ACCUM) { dv[o] += adv; dh[o] += adh; }
    else       { dv[o]  = adv; dh[o]  = adh; }
}

// ---------------- affinity: packed bf16 (wv,wh) for CG + 5-plane fp32 output ----------------
__global__ __launch_bounds__(256)
void aff2_kernel(const float* __restrict__ dv, const float* __restrict__ dh,
                 const float* __restrict__ llam, const float* __restrict__ lmu,
                 unsigned* __restrict__ wvh, float* __restrict__ aff)
{
    int bid = blockIdx.x;
    int n = bid >> 8, h = bid & 255, w = threadIdx.x;
    float mu = expf(lmu[0]), lam = expf(llam[0]);
    int rb = (n*256 + h)*256 + w;
    float wvv = (h < 255) ? expf(-mu * dv[rb]) : 0.f;
    float whv = (w < 255) ? expf(-mu * dh[rb]) : 0.f;
    unsigned pv = (unsigned)(unsigned short)f2bf(wvv);
    unsigned ph = (unsigned)(unsigned short)f2bf(whv);
    wvh[rb] = pv | (ph << 16);
    float w_up = (h > 0) ? expf(-mu * dv[rb - 256]) : 0.f;
    float w_lf = (w > 0) ? expf(-mu * dh[rb - 1])   : 0.f;
    float ctr  = w_up + wvv + w_lf + whv + lam;
    float* a = aff + ((size_t)n*5)*PLANE + h*256 + w;
    a[0]        = w_up;
    a[PLANE]    = wvv;
    a[2*PLANE]  = w_lf;
    a[3*PLANE]  = whv;
    a[4*PLANE]  = ctr;
}

// ---------------- block reductions (atomic into scal) ----------------
static __device__ __forceinline__ void reduce1(float v, float* dst, float* sh)
{
    #pragma unroll
    for (int o = 32; o > 0; o >>= 1) v += __shfl_down(v, o, 64);
    __syncthreads();
    if ((threadIdx.x & 63) == 0) sh[threadIdx.x >> 6] = v;
    __syncthreads();
    if (threadIdx.x == 0) atomicAdd(dst, sh[0]+sh[1]+sh[2]+sh[3]);
}
static __device__ __forceinline__ void reduce2(float a, float b, float* da, float* db, float* sh)
{
    #pragma unroll
    for (int o = 32; o > 0; o >>= 1) { a += __shfl_down(a, o, 64); b += __shfl_down(b, o, 64); }
    __syncthreads();
    if ((threadIdx.x & 63) == 0) { int wv = threadIdx.x >> 6; sh[wv] = a; sh[4+wv] = b; }
    __syncthreads();
    if (threadIdx.x == 0) {
        atomicAdd(da, sh[0]+sh[1]+sh[2]+sh[3]);
        atomicAdd(db, sh[4]+sh[5]+sh[6]+sh[7]);
    }
}

// ---------------- hand-rolled hierarchical grid barrier (512 blocks = 8 groups x 64) ----------------
// bar layout (uint idx, 128B-strided): [32*g] group counters g=0..7, [320] root, [352] generation.
// Agent-scope acq/rel atomics -> correct across non-coherent per-XCD L2s.
static __device__ __forceinline__ void grid_bar(unsigned* bar, unsigned* genp)
{
    __syncthreads();
    if (threadIdx.x == 0) {
        const unsigned gen = *genp;
        const int g = blockIdx.x & 7;
        unsigned my = __hip_atomic_fetch_add(&bar[32*g], 1u, __ATOMIC_ACQ_REL, __HIP_MEMORY_SCOPE_AGENT);
        bool released = false;
        if (my == 63u) {
            unsigned r = __hip_atomic_fetch_add(&bar[320], 1u, __ATOMIC_ACQ_REL, __HIP_MEMORY_SCOPE_AGENT);
            if (r == 7u) {
                #pragma unroll
                for (int i = 0; i < 8; i++)
                    __hip_atomic_store(&bar[32*i], 0u, __ATOMIC_RELAXED, __HIP_MEMORY_SCOPE_AGENT);
                __hip_atomic_store(&bar[320], 0u, __ATOMIC_RELAXED, __HIP_MEMORY_SCOPE_AGENT);
                __hip_atomic_fetch_add(&bar[352], 1u, __ATOMIC_ACQ_REL, __HIP_MEMORY_SCOPE_AGENT);
                released = true;
            }
        }
        if (!released)
            while (__hip_atomic_load(&bar[352], __ATOMIC_ACQUIRE, __HIP_MEMORY_SCOPE_AGENT) == gen)
                __builtin_amdgcn_s_sleep(2);
        *genp = gen + 1u;
    }
    __syncthreads();
}

// ============ persistent CG: all 100 iterations in ONE (normal) dispatch ============
// 512 blocks (16 img x 32 tiles of 64x32), 256 thr; capacity >= 2 blocks/CU via
// __launch_bounds__(256,2) -> all 512 co-resident -> hand-rolled barrier is safe.
// x,r,p,Ap live in REGISTERS (8 px/thread). Only the 1-px tile border of p crosses
// blocks per iteration (agent-scope stores to ph); scalars via device atomicAdd.
__global__ __launch_bounds__(256, 2)
void cg_persist(const unsigned* __restrict__ wvh, const float* __restrict__ mask,
                const float* __restrict__ src, const float* __restrict__ ybic,
                const float* __restrict__ llam,
                float* __restrict__ xout, float* __restrict__ ph,
                float* __restrict__ scal, unsigned* __restrict__ bar)
{
    __shared__ float s_pn[66][34];
    __shared__ float s_part[256], s_bs[32], s_red[8];

    const int tid = threadIdx.x;
    const int b = blockIdx.x;
    const int n = b >> 5, t = b & 31;
    const int tyo = (t >> 3) * 64, txo = (t & 7) * 32;
    const int tx = tid & 31, tyb = tid >> 5;
    const int w = txo + tx;
    const float lam = expf(llam[0]);
    unsigned gen = 0;

    const unsigned* wn = wvh + (size_t)n*PLANE;
    const float* ybn = ybic + (size_t)n*PLANE;
    float* phn = ph + (size_t)n*PLANE;   // halo publish buffer

    int idx[8];
    unsigned wc[8], wu[8], wl[8];
    float c1[8], rhs[8];
    #pragma unroll
    for (int i = 0; i < 8; i++) {
        int hhi = tyo + tyb + 8*i;
        idx[i] = hhi*256 + w;
        wc[i] = wn[idx[i]];
        wu[i] = (hhi > 0) ? wn[idx[i]-256] : 0u;
        wl[i] = (w > 0)   ? wn[idx[i]-1]   : 0u;
        int bi = n*1024 + (hhi>>3)*32 + (w>>3);
        float mv = mask[bi];
        c1[i]  = lam*mv*(1.f/4096.f);
        rhs[i] = lam*mv*src[bi]*(1.f/64.f);
    }

    // avgpool(8x8) of the LDS tile -> s_bs[32]
    #define POOL_BLOCK() do { \
        __syncthreads(); \
        { int segrow_ = tid >> 2, segcol_ = tid & 3; \
          const float* rw_ = &s_pn[1 + segrow_][1 + segcol_*8]; \
          s_part[tid] = rw_[0]+rw_[1]+rw_[2]+rw_[3]+rw_[4]+rw_[5]+rw_[6]+rw_[7]; } \
        __syncthreads(); \
        if (tid < 32) { int brow_ = tid >> 2, bcol_ = tid & 3; float s_ = 0.f; \
          _Pragma("unroll") \
          for (int rr_ = 0; rr_ < 8; rr_++) s_ += s_part[(brow_*8 + rr_)*4 + bcol_]; \
          s_bs[tid] = s_; } \
        __syncthreads(); \
    } while (0)

    // publish tile-border p values (rows 0/63, cols 0/31) — agent scope
    #define PUBLISH_P() do { \
        if (tyb == 0) stg_ag(phn + idx[0], pv[0]); \
        if (tyb == 7) stg_ag(phn + idx[7], pv[7]); \
        if (tx == 0 || tx == 31) { \
            _Pragma("unroll") \
            for (int i_ = 0; i_ < 8; i_++) stg_ag(phn + idx[i_], pv[i_]); \
        } \
    } while (0)

    // read 1-px halo ring of p from neighbors' published borders — agent scope
    #define HALO_LOAD() do { \
        if (tid < 192) { \
            int y_, x_; \
            if      (tid < 32)  { y_ = tyo - 1;         x_ = txo + tid;       } \
            else if (tid < 64)  { y_ = tyo + 64;        x_ = txo + (tid-32);  } \
            else if (tid < 128) { y_ = tyo + (tid-64);  x_ = txo - 1;         } \
            else                { y_ = tyo + (tid-128); x_ = txo + 32;        } \
            float v_ = 0.f; \
            if (y_ >= 0 && y_ < 256 && x_ >= 0 && x_ < 256) v_ = ldg_ag(phn + y_*256 + x_); \
            s_pn[y_ - tyo + 1][x_ - txo + 1] = v_; \
        } \
    } while (0)

    auto matvec = [&](int i) -> float {
        int yy = 1 + tyb + 8*i, xx = 1 + tx;
        float wvd = bf2f((short)(wc[i] & 0xffff));
        float whr = bf2f((short)(wc[i] >> 16));
        float wvu = bf2f((short)(wu[i] & 0xffff));
        float whl = bf2f((short)(wl[i] >> 16));
        float s = wvu*s_pn[yy-1][xx] + wvd*s_pn[yy+1][xx]
                + whl*s_pn[yy][xx-1] + whr*s_pn[yy][xx+1];
        float deg = wvu+wvd+whl+whr;
        return deg*s_pn[yy][xx] - s + c1[i]*s_bs[i*4 + (tx>>3)];
    };

    float xv[8], rv[8], pv[8], apv[8];

    // ---------- init: x0 = ybic, r0 = p0 = b - A x0, g0 = ||r0||^2 ----------
    #pragma unroll
    for (int i = 0; i < 8; i++) {
        xv[i] = ybn[idx[i]];
        s_pn[1 + tyb + 8*i][1 + tx] = xv[i];
    }
    if (tid < 192) {
        int y, xx;
        if      (tid < 32)  { y = tyo - 1;         xx = txo + tid;       }
        else if (tid < 64)  { y = tyo + 64;        xx = txo + (tid-32);  }
        else if (tid < 128) { y = tyo + (tid-64);  xx = txo - 1;         }
        else                { y = tyo + (tid-128); xx = txo + 32;        }
        float v = 0.f;
        if (y >= 0 && y < 256 && xx >= 0 && xx < 256) v = ybn[y*256 + xx];
        s_pn[y - tyo + 1][xx - txo + 1] = v;
    }
    POOL_BLOCK();
    float g0 = 0.f;
    #pragma unroll
    for (int i = 0; i < 8; i++) {
        float ax = matvec(i);
        float r0 = rhs[i] - ax;
        rv[i] = r0; pv[i] = r0;
        g0 += r0*r0;
    }
    PUBLISH_P();
    reduce1(g0, &scal[0], s_red);
    grid_bar(bar, &gen);

    // ---------- k = 0: Ap0 = A p0; reduce pAp0, ApAp0 ----------
    #pragma unroll
    for (int i = 0; i < 8; i++) s_pn[1 + tyb + 8*i][1 + tx] = pv[i];
    HALO_LOAD();
    POOL_BLOCK();
    {
        float pap = 0.f, apap = 0.f;
        #pragma unroll
        for (int i = 0; i < 8; i++) {
            float ap = matvec(i);
            apv[i] = ap;
            pap  += pv[i]*ap;
            apap += ap*ap;
        }
        reduce2(pap, apap, &scal[128], &scal[256], s_red);
    }
    grid_bar(bar, &gen);

    // ---------- main loop: k = 1..99 ----------
    for (int k = 1; k <= 99; k++) {
        float gprev = ldg_ag(&scal[k-1]);
        float paps  = ldg_ag(&scal[128+k-1]);
        float apaps = ldg_ag(&scal[256+k-1]);
        float alpha = gprev / paps;
        float beta  = (alpha*alpha*apaps - gprev) / gprev;
        float gsum = 0.f;
        #pragma unroll
        for (int i = 0; i < 8; i++) {
            float rN = fmaf(-alpha, apv[i], rv[i]);
            xv[i] = fmaf(alpha, pv[i], xv[i]);
            float pN = fmaf(beta, pv[i], rN);
            rv[i] = rN; pv[i] = pN;
            gsum += rN*rN;
            s_pn[1 + tyb + 8*i][1 + tx] = pN;
        }
        PUBLISH_P();
        reduce1(gsum, &scal[k], s_red);
        grid_bar(bar, &gen);              // halos + g[k] visible

        HALO_LOAD();
        POOL_BLOCK();
        float pap = 0.f, apap = 0.f;
        #pragma unroll
        for (int i = 0; i < 8; i++) {
            float ap = matvec(i);
            apv[i] = ap;
            pap  += pv[i]*ap;
            apap += ap*ap;
        }
        reduce2(pap, apap, &scal[128+k], &scal[256+k], s_red);
        grid_bar(bar, &gen);              // pAp[k], ApAp[k] visible
    }

    // ---------- tail: x += alpha_99 * p_99; write x ----------
    float alphaT = ldg_ag(&scal[99]) / ldg_ag(&scal[128+99]);
    float* xn = xout + (size_t)n*PLANE;
    #pragma unroll
    for (int i = 0; i < 8; i++) xn[idx[i]] = fmaf(alphaT, pv[i], xv[i]);

    #undef POOL_BLOCK
    #undef PUBLISH_P
    #undef HALO_LOAD
}

// ---------------- host ----------------
extern "C" void kernel_launch(void* const* d_in, const int* in_sizes, int n_in,
                              void* d_out, int out_size, void* d_ws, size_t ws_size,
                              hipStream_t stream)
{
    (void)in_sizes; (void)n_in; (void)out_size; (void)ws_size;
    const float* guide = (const float*)d_in[0];
    const float* source= (const float*)d_in[1];
    const float* mask  = (const float*)d_in[2];
    const float* ybic  = (const float*)d_in[3];
    const float* gw1 = (const float*)d_in[4];  const float* gb1 = (const float*)d_in[5];
    const float* gw2 = (const float*)d_in[6];  const float* gb2 = (const float*)d_in[7];
    const float* sw1 = (const float*)d_in[8];  const float* sb1 = (const float*)d_in[9];
    const float* sw2 = (const float*)d_in[10]; const float* sb2 = (const float*)d_in[11];
    const float* vw1 = (const float*)d_in[12]; const float* vb1 = (const float*)d_in[13];
    const float* vw2 = (const float*)d_in[14]; const float* vb2 = (const float*)d_in[15];
    const float* vw3 = (const float*)d_in[16]; const float* vb3 = (const float*)d_in[17];
    const float* llam = (const float*)d_in[18];
    const float* lmu  = (const float*)d_in[19];

    float* out     = (float*)d_out;
    float* x_out   = out;                 // y_pred (16,1,256,256)
    float* var_out = out + 1048576;       // var
    float* aff_out = out + 2097152;       // aff (16,5,256,256)

    // ---- workspace layout (small persistent objects FIRST; CG halo buffer
    //      aliases the dead conv temporaries) ----
    char* ws = (char*)d_ws;
    float*    scal = (float*)ws;                        // [0, 2 KiB)  (indices 0..355 used)
    bf16*     wpk1 = (bf16*)(ws + 2048);                // 18 KiB each
    bf16*     wpk2 = (bf16*)(ws + 2048 + 18432);
    bf16*     wpk3 = (bf16*)(ws + 2048 + 36864);        // ends at 57344
    unsigned* bar  = (unsigned*)(ws + 59392);           // 1.5 KiB barrier counters
    unsigned* wvh  = (unsigned*)(ws + 65536);           // [64 KiB, 64 KiB + 4 MiB)
    char*     A    = ws + 65536 + (size_t)NB*PLANE*4;   // shared region
    // conv-phase mapping of A:
    bf16*  tmp1 = (bf16*)(A);                                  // 64 MiB
    bf16*  tmp2 = (bf16*)(A + (size_t)NB*32*PLANE*2);          // 64 MiB
    float* dv   = (float*)(A + (size_t)NB*32*PLANE*4);         // 4 MiB
    float* dh   = (float*)(A + (size_t)NB*32*PLANE*4 + (size_t)NB*PLANE*4);
    // CG-phase mapping of A (conv temporaries dead by then):
    float* phalo = (float*)A;                                  // 4 MiB p-halo publish

    dim3 cgrid(16, 16, NB);

    // zero scal + barrier counters (covers [0, 2KiB) and barrier region; weights
    // repacked after this memset, so wiping [0,64KiB) would also be fine)
    hipMemsetAsync(scal, 0, 2048, stream);
    hipMemsetAsync(bar, 0, 2048, stream);

    // repack the three 32->32 conv weights into MFMA fragment layout
    wrepack3<<<108,256,0,stream>>>(gw2, sw2, vw2, wpk1, wpk2, wpk3);

    // feature branch g = conv(relu(conv(guide)))
    conv3x3_first<3,3,true><<<cgrid,256,0,stream>>>(guide, guide, gw1, gb1, tmp1);
    conv3x3_mfma<false><<<cgrid,256,0,stream>>>(tmp1, wpk1, gb2, tmp2);
    dvdh_cl<false><<<4096,256,0,stream>>>(tmp2, dv, dh);
    // feature branch s = conv(relu(conv(y_bicubic)))
    conv3x3_first<1,1,true><<<cgrid,256,0,stream>>>(ybic, ybic, sw1, sb1, tmp1);
    conv3x3_mfma<false><<<cgrid,256,0,stream>>>(tmp1, wpk2, sb2, tmp2);
    dvdh_cl<true><<<4096,256,0,stream>>>(tmp2, dv, dh);
    aff2_kernel<<<4096,256,0,stream>>>(dv, dh, llam, lmu, wvh, aff_out);
    // variance branch
    conv3x3_first<4,3,true><<<cgrid,256,0,stream>>>(guide, ybic, vw1, vb1, tmp1);
    conv3x3_mfma<true><<<cgrid,256,0,stream>>>(tmp1, wpk3, vb2, tmp2);
    conv3x3_last<<<4096,256,0,stream>>>(tmp2, vw3, vb3, var_out);

    // CG: ONE persistent dispatch (init + 100 iterations + tail), normal launch,
    // hand-rolled grid barrier (all 512 blocks co-resident at 2 blocks/CU).
    cg_persist<<<512,256,0,stream>>>(wvh, mask, source, ybic, llam,
                                     x_out, phalo, scal, bar);
}

// Round 3
// 1271.268 us; speedup vs baseline: 6.5943x; 6.5943x over previous
//
#include <hip/hip_runtime.h>
#include <hip/hip_bf16.h>

typedef __hip_bfloat16 bf16;
typedef __attribute__((ext_vector_type(8))) short short8;
typedef __attribute__((ext_vector_type(4))) float f32x4;

#define NB 16
#define PLANE (256*256)

static __device__ __forceinline__ short f2bf(float v){
    __hip_bfloat16 h = __float2bfloat16(v);
    short s; __builtin_memcpy(&s, &h, 2); return s;
}
static __device__ __forceinline__ float bf2f(short s){
    union { unsigned u; float f; } cv;
    cv.u = ((unsigned)(unsigned short)s) << 16; return cv.f;
}

// agent-scope (cross-XCD coherent, uncached) accesses — bypass per-XCD L2
static __device__ __forceinline__ void  stg_ag(float* p, float v){
    __hip_atomic_store(p, v, __ATOMIC_RELAXED, __HIP_MEMORY_SCOPE_AGENT);
}
static __device__ __forceinline__ float ldg_ag(const float* p){
    return __hip_atomic_load(p, __ATOMIC_RELAXED, __HIP_MEMORY_SCOPE_AGENT);
}
static __device__ __forceinline__ void  stu_ag(unsigned* p, unsigned v){
    __hip_atomic_store(p, v, __ATOMIC_RELAXED, __HIP_MEMORY_SCOPE_AGENT);
}
static __device__ __forceinline__ unsigned ldu_ag(const unsigned* p){
    return __hip_atomic_load(p, __ATOMIC_RELAXED, __HIP_MEMORY_SCOPE_AGENT);
}

// ---------------- first-layer conv 3x3 (small CIN, VALU), output channel-last bf16 ----------------
template<int CIN, int SPLIT, bool RELU>
__global__ __launch_bounds__(256)
void conv3x3_first(const float* __restrict__ in, const float* __restrict__ in2,
                   const float* __restrict__ wgt, const float* __restrict__ bias,
                   bf16* __restrict__ out)
{
    __shared__ float s_in[CIN][18][18];
    __shared__ float s_w[CIN*9*32];
    const int n  = blockIdx.z;
    const int ty0 = blockIdx.y * 16, tx0 = blockIdx.x * 16;
    const int tid = threadIdx.x;

    for (int idx = tid; idx < CIN*9*32; idx += 256) {
        int co = idx & 31; int rest = idx >> 5;     // rest = ci*9 + k
        s_w[idx] = wgt[(co*CIN + rest/9)*9 + rest%9];
    }
    for (int idx = tid; idx < CIN*18*18; idx += 256) {
        int ci = idx / (18*18); int rr = idx % (18*18);
        int yy = rr / 18, xx = rr % 18;
        int y = ty0 + yy - 1, x = tx0 + xx - 1;
        float v = 0.f;
        if (y >= 0 && y < 256 && x >= 0 && x < 256) {
            if (ci < SPLIT) v = in [((size_t)(n*SPLIT + ci)*256 + y)*256 + x];
            else            v = in2[((size_t)(n*(CIN-SPLIT) + (ci-SPLIT))*256 + y)*256 + x];
        }
        s_in[ci][yy][xx] = v;
    }
    __syncthreads();

    const int ty = tid >> 4, tx = tid & 15;
    float acc[32];
    #pragma unroll
    for (int co = 0; co < 32; co++) acc[co] = bias[co];

    #pragma unroll
    for (int ci = 0; ci < CIN; ci++) {
        #pragma unroll
        for (int ky = 0; ky < 3; ky++)
        #pragma unroll
        for (int kx = 0; kx < 3; kx++) {
            float v = s_in[ci][ty+ky][tx+kx];
            const float* wp = &s_w[(ci*9 + ky*3 + kx)*32];
            #pragma unroll
            for (int co = 0; co < 32; co++) acc[co] = fmaf(v, wp[co], acc[co]);
        }
    }
    const int y = ty0 + ty, x = tx0 + tx;
    size_t base = (((size_t)n*256 + y)*256 + x)*32;
    #pragma unroll
    for (int c = 0; c < 32; c += 8) {
        short8 vv;
        #pragma unroll
        for (int j = 0; j < 8; j++) {
            float v = acc[c+j];
            if (RELU) v = fmaxf(v, 0.f);
            vv[j] = f2bf(v);
        }
        *(short8*)((short*)out + base + c) = vv;
    }
}

// ---------------- weight repack for MFMA convs: [co][ci][tap] f32 -> [tap][co][ci] bf16 ----------------
__global__ __launch_bounds__(256)
void wrepack3(const float* __restrict__ a, const float* __restrict__ b,
              const float* __restrict__ c,
              bf16* __restrict__ oa, bf16* __restrict__ ob, bf16* __restrict__ oc)
{
    int j = blockIdx.x*256 + threadIdx.x;        // 0..27647
    if (j >= 3*9216) return;
    int set = j / 9216, r = j % 9216;
    int tap = r >> 10, rem = r & 1023, co = rem >> 5, ci = rem & 31;
    const float* src = (set == 0) ? a : (set == 1) ? b : c;
    bf16* dst = (set == 0) ? oa : (set == 1) ? ob : oc;
    dst[r] = __float2bfloat16(src[(co*32 + ci)*9 + tap]);
}

// ---------------- heavy conv 3x3 (32->32) via MFMA, channel-last bf16 in/out ----------------
template<bool RELU>
__global__ __launch_bounds__(256)
void conv3x3_mfma(const bf16* __restrict__ in, const bf16* __restrict__ wpk,
                  const float* __restrict__ bias, bf16* __restrict__ out)
{
    const int lane = threadIdx.x & 63, wid = threadIdx.x >> 6;
    const int m = lane & 15, quad = lane >> 4, k0 = quad*8;
    const int n  = blockIdx.z;
    const int x0 = blockIdx.x * 16;
    const int y0 = blockIdx.y * 16 + wid * 4;

    const short* wp = (const short*)wpk;
    short8 bw[2][9];
    #pragma unroll
    for (int g = 0; g < 2; g++)
        #pragma unroll
        for (int tap = 0; tap < 9; tap++)
            bw[g][tap] = *(const short8*)(wp + ((tap*32 + g*16 + m)*32 + k0));
    const float b0 = bias[m], b1 = bias[16 + m];

    const short* inp = (const short*)in + (size_t)n*PLANE*32;
    short* outp = (short*)out + (size_t)n*PLANE*32;

    #pragma unroll
    for (int r = 0; r < 4; r++) {
        const int y = y0 + r;
        f32x4 acc0 = { b0, b0, b0, b0 };
        f32x4 acc1 = { b1, b1, b1, b1 };
        #pragma unroll
        for (int ky = 0; ky < 3; ky++) {
            const int yy = y + ky - 1;
            const bool yok = (unsigned)yy < 256u;
            #pragma unroll
            for (int kx = 0; kx < 3; kx++) {
                const int xp = x0 + kx - 1 + m;
                short8 a = { 0,0,0,0,0,0,0,0 };
                if (yok && (unsigned)xp < 256u)
                    a = *(const short8*)(inp + ((size_t)yy*256 + xp)*32 + k0);
                acc0 = __builtin_amdgcn_mfma_f32_16x16x32_bf16(a, bw[0][ky*3+kx], acc0, 0, 0, 0);
                acc1 = __builtin_amdgcn_mfma_f32_16x16x32_bf16(a, bw[1][ky*3+kx], acc1, 0, 0, 0);
            }
        }
        #pragma unroll
        for (int reg = 0; reg < 4; reg++) {
            int px = x0 + quad*4 + reg;
            size_t idx = ((size_t)y*256 + px)*32;
            float v0 = acc0[reg], v1 = acc1[reg];
            if (RELU) { v0 = fmaxf(v0, 0.f); v1 = fmaxf(v1, 0.f); }
            outp[idx + m]      = f2bf(v0);
            outp[idx + 16 + m] = f2bf(v1);
        }
    }
}

// ---------------- final conv 3x3 (32->1), channel-last input ----------------
__global__ __launch_bounds__(256)
void conv3x3_last(const bf16* __restrict__ in, const float* __restrict__ wgt,
                  const float* __restrict__ bias, float* __restrict__ out)
{
    __shared__ float s_w[288];
    int tid = threadIdx.x;
    for (int i = tid; i < 288; i += 256) s_w[i] = wgt[i];
    __syncthreads();
    int gid = blockIdx.x*256 + tid;
    int n = gid >> 16, h = (gid >> 8) & 255, w = gid & 255;
    const short* inp = (const short*)in + (size_t)n*PLANE*32;
    float sum = bias[0];
    #pragma unroll
    for (int ky = 0; ky < 3; ky++) {
        int yy = h + ky - 1;
        if ((unsigned)yy >= 256u) continue;
        #pragma unroll
        for (int kx = 0; kx < 3; kx++) {
            int xx = w + kx - 1;
            if ((unsigned)xx >= 256u) continue;
            const short8* pp = (const short8*)(inp + ((size_t)yy*256 + xx)*32);
            int tap = ky*3 + kx;
            #pragma unroll
            for (int c4 = 0; c4 < 4; c4++) {
                short8 v = pp[c4];
                #pragma unroll
                for (int j = 0; j < 8; j++)
                    sum = fmaf(bf2f(v[j]), s_w[(c4*8+j)*9 + tap], sum);
            }
        }
    }
    out[gid] = sum;
}

// ---------------- squared neighbor diffs over 32 channels, channel-last ----------------
template<bool ACCUM>
__global__ __launch_bounds__(256)
void dvdh_cl(const bf16* __restrict__ f, float* __restrict__ dv, float* __restrict__ dh)
{
    int bid = blockIdx.x;
    int n = bid >> 8, i = bid & 255, j = threadIdx.x;
    const short8* pc = (const short8*)((const short*)f + (((size_t)n*256 + i)*256 + j)*32);
    const short8* pr = (j < 255) ? pc + 4    : pc;
    const short8* pd = (i < 255) ? pc + 1024 : pc;
    float adv = 0.f, adh = 0.f;
    #pragma unroll
    for (int c4 = 0; c4 < 4; c4++) {
        short8 sc = pc[c4], sr = pr[c4], sd = pd[c4];
        #pragma unroll
        for (int e = 0; e < 8; e++) {
            float fc = bf2f(sc[e]);
            float d1 = bf2f(sr[e]) - fc;
            float d2 = bf2f(sd[e]) - fc;
            adh = fmaf(d1, d1, adh);
            adv = fmaf(d2, d2, adv);
        }
    }
    int o = (n*256 + i)*256 + j;
    if (ACCUM) { dv[o] += adv; dh[o] += adh; }
    else       { dv[o]  = adv; dh[o]  = adh; }
}

// ---------------- affinity: packed bf16 (wv,wh) for CG + 5-plane fp32 output ----------------
__global__ __launch_bounds__(256)
void aff2_kernel(const float* __restrict__ dv, const float* __restrict__ dh,
                 const float* __restrict__ llam, const float* __restrict__ lmu,
                 unsigned* __restrict__ wvh, float* __restrict__ aff)
{
    int bid = blockIdx.x;
    int n = bid >> 8, h = bid & 255, w = threadIdx.x;
    float mu = expf(lmu[0]), lam = expf(llam[0]);
    int rb = (n*256 + h)*256 + w;
    float wvv = (h < 255) ? expf(-mu * dv[rb]) : 0.f;
    float whv = (w < 255) ? expf(-mu * dh[rb]) : 0.f;
    unsigned pv = (unsigned)(unsigned short)f2bf(wvv);
    unsigned ph = (unsigned)(unsigned short)f2bf(whv);
    wvh[rb] = pv | (ph << 16);
    float w_up = (h > 0) ? expf(-mu * dv[rb - 256]) : 0.f;
    float w_lf = (w > 0) ? expf(-mu * dh[rb - 1])   : 0.f;
    float ctr  = w_up + wvv + w_lf + whv + lam;
    float* a = aff + ((size_t)n*5)*PLANE + h*256 + w;
    a[0]        = w_up;
    a[PLANE]    = wvv;
    a[2*PLANE]  = w_lf;
    a[3*PLANE]  = whv;
    a[4*PLANE]  = ctr;
}

// ============ persistent CG: all 100 iterations, ONE dispatch, ONE barrier/iter ============
// 512 blocks (16 img x 32 tiles of 64x32), 256 thr, capacity >= 2 blocks/CU.
// x,r,p,Ap in REGISTERS (8 px/thread). Halo p is RECONSTRUCTED locally from the CG
// recurrence (rh,ph registers per halo cell) using the neighbor's published border Ap
// (bit-exact). One flag-based barrier per iteration carries the 3 dot products as a
// tree reduction folded into block 0 — zero atomic RMWs, zero acq/rel cache ops.
__global__ __launch_bounds__(256, 2)
void cg_persist(const unsigned* __restrict__ wvh, const float* __restrict__ mask,
                const float* __restrict__ src, const float* __restrict__ ybic,
                const float* __restrict__ llam, float* __restrict__ xout,
                float* __restrict__ hbuf0, float* __restrict__ hbuf1,
                float* __restrict__ part, unsigned* __restrict__ arrive,
                unsigned* __restrict__ genp, float* __restrict__ scal3)
{
    __shared__ float s_pn[66][34];
    __shared__ float s_part[256], s_bs[32];
    __shared__ float s_w3[12], s_out[3];

    const int tid = threadIdx.x;
    const int b = blockIdx.x;
    const int n = b >> 5, t = b & 31;
    const int tyo = (t >> 3) * 64, txo = (t & 7) * 32;
    const int tx = tid & 31, tyb = tid >> 5;
    const int w = txo + tx;
    const float lam = expf(llam[0]);

    const unsigned* wn = wvh + (size_t)n*PLANE;
    const float* ybn = ybic + (size_t)n*PLANE;
    float* h0n = hbuf0 + (size_t)n*PLANE;
    float* h1n = hbuf1 + (size_t)n*PLANE;

    // per-thread stencil constants
    int idx[8];
    unsigned wc[8], wu[8], wl[8];
    float c1[8], rhs[8];
    #pragma unroll
    for (int i = 0; i < 8; i++) {
        int hhi = tyo + tyb + 8*i;
        idx[i] = hhi*256 + w;
        wc[i] = wn[idx[i]];
        wu[i] = (hhi > 0) ? wn[idx[i]-256] : 0u;
        wl[i] = (w > 0)   ? wn[idx[i]-1]   : 0u;
        int bi = n*1024 + (hhi>>3)*32 + (w>>3);
        float mv = mask[bi];
        c1[i]  = lam*mv*(1.f/4096.f);
        rhs[i] = lam*mv*src[bi]*(1.f/64.f);
    }

    // halo-cell ownership: tid<192 owns one cell of the 1-px ring (no corners)
    const bool hthr = (tid < 192);
    int hy = 0, hx = 0; bool hin = false; int hoff = 0;
    if (hthr) {
        if      (tid < 32)  { hy = tyo - 1;         hx = txo + tid;       }
        else if (tid < 64)  { hy = tyo + 64;        hx = txo + (tid-32);  }
        else if (tid < 128) { hy = tyo + (tid-64);  hx = txo - 1;         }
        else                { hy = tyo + (tid-128); hx = txo + 32;        }
        hin = (hy >= 0 && hy < 256 && hx >= 0 && hx < 256);
        hoff = hy*256 + hx;
    }
    const int hsy = hy - tyo + 1, hsx = hx - txo + 1;

    // avgpool(8x8) of the LDS tile -> s_bs[32]
    #define POOL_BLOCK() do { \
        __syncthreads(); \
        { int segrow_ = tid >> 2, segcol_ = tid & 3; \
          const float* rw_ = &s_pn[1 + segrow_][1 + segcol_*8]; \
          s_part[tid] = rw_[0]+rw_[1]+rw_[2]+rw_[3]+rw_[4]+rw_[5]+rw_[6]+rw_[7]; } \
        __syncthreads(); \
        if (tid < 32) { int brow_ = tid >> 2, bcol_ = tid & 3; float s_ = 0.f; \
          _Pragma("unroll") \
          for (int rr_ = 0; rr_ < 8; rr_++) s_ += s_part[(brow_*8 + rr_)*4 + bcol_]; \
          s_bs[tid] = s_; } \
        __syncthreads(); \
    } while (0)

    // publish tile-border values of arr[] to buf (agent-scope, uncached)
    #define PUBLISH_B(arr, buf) do { \
        if (tyb == 0) stg_ag((buf) + idx[0], arr[0]); \
        if (tyb == 7) stg_ag((buf) + idx[7], arr[7]); \
        if (tx == 0 || tx == 31) { \
            _Pragma("unroll") \
            for (int i_ = 0; i_ < 8; i_++) stg_ag((buf) + idx[i_], arr[i_]); \
        } \
    } while (0)

    auto matvec = [&](int i) -> float {
        int yy = 1 + tyb + 8*i, xx = 1 + tx;
        float wvd = bf2f((short)(wc[i] & 0xffff));
        float whr = bf2f((short)(wc[i] >> 16));
        float wvu = bf2f((short)(wu[i] & 0xffff));
        float whl = bf2f((short)(wl[i] >> 16));
        float s = wvu*s_pn[yy-1][xx] + wvd*s_pn[yy+1][xx]
                + whl*s_pn[yy][xx-1] + whr*s_pn[yy][xx+1];
        float deg = wvu+wvd+whl+whr;
        return deg*s_pn[yy][xx] - s + c1[i]*s_bs[i*4 + (tx>>3)];
    };

    // flag-based barrier + fused 3-way grid reduction.
    // leader publishes 3 block partials + seq flag (ordered by vmcnt drain);
    // block 0 polls 512 flags (2/thread), tree-reduces, writes sums + gen;
    // others poll gen. All uncached relaxed — no RMW, no acq/rel cache ops.
    auto bar_red3 = [&](unsigned seq, float va, float vb, float vc){
        #pragma unroll
        for (int o = 32; o > 0; o >>= 1) {
            va += __shfl_down(va, o, 64);
            vb += __shfl_down(vb, o, 64);
            vc += __shfl_down(vc, o, 64);
        }
        __syncthreads();
        if ((tid & 63) == 0) { int wv = tid >> 6; s_w3[wv*3]=va; s_w3[wv*3+1]=vb; s_w3[wv*3+2]=vc; }
        __syncthreads();   // all waves' halo publishes drained (vmcnt) before flag
        if (tid == 0) {
            float pa = s_w3[0]+s_w3[3]+s_w3[6]+s_w3[9];
            float pb = s_w3[1]+s_w3[4]+s_w3[7]+s_w3[10];
            float pc = s_w3[2]+s_w3[5]+s_w3[8]+s_w3[11];
            stg_ag(&part[b], pa);
            stg_ag(&part[512+b], pb);
            stg_ag(&part[1024+b], pc);
            asm volatile("s_waitcnt vmcnt(0)" ::: "memory");
            stu_ag(&arrive[b], seq);
        }
        if (blockIdx.x == 0) {
            __syncthreads();   // protect s_w3 WAR vs leader's read above
            while (ldu_ag(&arrive[2*tid]) != seq || ldu_ag(&arrive[2*tid+1]) != seq)
                __builtin_amdgcn_s_sleep(2);
            float pa = ldg_ag(&part[2*tid])      + ldg_ag(&part[2*tid+1]);
            float pb = ldg_ag(&part[512+2*tid])  + ldg_ag(&part[512+2*tid+1]);
            float pc = ldg_ag(&part[1024+2*tid]) + ldg_ag(&part[1024+2*tid+1]);
            #pragma unroll
            for (int o = 32; o > 0; o >>= 1) {
                pa += __shfl_down(pa, o, 64);
                pb += __shfl_down(pb, o, 64);
                pc += __shfl_down(pc, o, 64);
            }
            if ((tid & 63) == 0) { int wv = tid >> 6; s_w3[wv*3]=pa; s_w3[wv*3+1]=pb; s_w3[wv*3+2]=pc; }
            __syncthreads();
            if (tid == 0) {
                float fa = s_w3[0]+s_w3[3]+s_w3[6]+s_w3[9];
                float fb = s_w3[1]+s_w3[4]+s_w3[7]+s_w3[10];
                float fc = s_w3[2]+s_w3[5]+s_w3[8]+s_w3[11];
                stg_ag(&scal3[0], fa); stg_ag(&scal3[1], fb); stg_ag(&scal3[2], fc);
                asm volatile("s_waitcnt vmcnt(0)" ::: "memory");
                stu_ag(genp, seq);
                s_out[0] = fa; s_out[1] = fb; s_out[2] = fc;
            }
        } else {
            if (tid == 0) {
                while (ldu_ag(genp) != seq) __builtin_amdgcn_s_sleep(2);
                s_out[0] = ldg_ag(&scal3[0]);
                s_out[1] = ldg_ag(&scal3[1]);
                s_out[2] = ldg_ag(&scal3[2]);
            }
        }
        __syncthreads();
    };

    float xv[8], rv[8], pv[8], apv[8];

    // ---------- phase I: x0 = ybic, r0 = p0 = b - A x0; reduce g0; publish r0 border -> h1 ----------
    #pragma unroll
    for (int i = 0; i < 8; i++) {
        xv[i] = ybn[idx[i]];
        s_pn[1 + tyb + 8*i][1 + tx] = xv[i];
    }
    if (hthr) s_pn[hsy][hsx] = hin ? ybn[hoff] : 0.f;
    POOL_BLOCK();
    float g0 = 0.f;
    #pragma unroll
    for (int i = 0; i < 8; i++) {
        float ax = matvec(i);
        float r0 = rhs[i] - ax;
        rv[i] = r0; pv[i] = r0;
        g0 += r0*r0;
    }
    PUBLISH_B(pv, h1n);
    bar_red3(1u, g0, 0.f, 0.f);
    float gR = s_out[0];

    // ---------- phase II (k=0): halo rh=ph=r0(published); Ap0 = A p0; reduce pAp0, ApAp0; publish Ap0 -> h0 ----------
    float rh = 0.f, phh = 0.f;
    if (hthr) {
        float v = hin ? ldg_ag(h1n + hoff) : 0.f;
        rh = v; phh = v;
        s_pn[hsy][hsx] = phh;
    }
    #pragma unroll
    for (int i = 0; i < 8; i++) s_pn[1 + tyb + 8*i][1 + tx] = pv[i];
    POOL_BLOCK();
    {
        float pap = 0.f, apap = 0.f;
        #pragma unroll
        for (int i = 0; i < 8; i++) {
            float ap = matvec(i);
            apv[i] = ap;
            pap  += pv[i]*ap;
            apap += ap*ap;
        }
        PUBLISH_B(apv, h0n);
        bar_red3(2u, 0.f, pap, apap);
    }
    float pApR = s_out[1], ApApR = s_out[2];

    // ---------- main loop k=1..99: ONE barrier per iteration ----------
    for (int k = 1; k <= 99; k++) {
        float alpha = gR / pApR;
        float beta  = (alpha*alpha*ApApR - gR) / gR;
        float* rb_ = ((k-1) & 1) ? h1n : h0n;   // neighbor's Ap_{k-1} border
        float* wb_ = (k & 1)     ? h1n : h0n;   // our Ap_k border
        if (hthr) {
            float Aph = hin ? ldg_ag(rb_ + hoff) : 0.f;
            rh  = fmaf(-alpha, Aph, rh);
            phh = fmaf(beta, phh, rh);
            s_pn[hsy][hsx] = phh;
        }
        float gsum = 0.f;
        #pragma unroll
        for (int i = 0; i < 8; i++) {
            float rN = fmaf(-alpha, apv[i], rv[i]);
            xv[i] = fmaf(alpha, pv[i], xv[i]);
            float pN = fmaf(beta, pv[i], rN);
            rv[i] = rN; pv[i] = pN;
            gsum += rN*rN;
            s_pn[1 + tyb + 8*i][1 + tx] = pN;
        }
        POOL_BLOCK();
        float pap = 0.f, apap = 0.f;
        #pragma unroll
        for (int i = 0; i < 8; i++) {
            float ap = matvec(i);
            apv[i] = ap;
            pap  += pv[i]*ap;
            apap += ap*ap;
        }
        PUBLISH_B(apv, wb_);
        bar_red3((unsigned)(k + 2), gsum, pap, apap);
        gR = s_out[0]; pApR = s_out[1]; ApApR = s_out[2];
    }

    // ---------- tail: x += alpha_100 * p_99 ----------
    float alphaT = gR / pApR;
    float* xn = xout + (size_t)n*PLANE;
    #pragma unroll
    for (int i = 0; i < 8; i++) xn[idx[i]] = fmaf(alphaT, pv[i], xv[i]);

    #undef POOL_BLOCK
    #undef PUBLISH_B
}

// ---------------- host ----------------
extern "C" void kernel_launch(void* const* d_in, const int* in_sizes, int n_in,
                              void* d_out, int out_size, void* d_ws, size_t ws_size,
                              hipStream_t stream)
{
    (void)in_sizes; (void)n_in; (void)out_size; (void)ws_size;
    const float* guide = (const float*)d_in[0];
    const float* source= (const float*)d_in[1];
    const float* mask  = (const float*)d_in[2];
    const float* ybic  = (const float*)d_in[3];
    const float* gw1 = (const float*)d_in[4];  const float* gb1 = (const float*)d_in[5];
    const float* gw2 = (const float*)d_in[6];  const float* gb2 = (const float*)d_in[7];
    const float* sw1 = (const float*)d_in[8];  const float* sb1 = (const float*)d_in[9];
    const float* sw2 = (const float*)d_in[10]; const float* sb2 = (const float*)d_in[11];
    const float* vw1 = (const float*)d_in[12]; const float* vb1 = (const float*)d_in[13];
    const float* vw2 = (const float*)d_in[14]; const float* vb2 = (const float*)d_in[15];
    const float* vw3 = (const float*)d_in[16]; const float* vb3 = (const float*)d_in[17];
    const float* llam = (const float*)d_in[18];
    const float* lmu  = (const float*)d_in[19];

    float* out     = (float*)d_out;
    float* x_out   = out;                 // y_pred (16,1,256,256)
    float* var_out = out + 1048576;       // var
    float* aff_out = out + 2097152;       // aff (16,5,256,256)

    // ---- workspace layout ----
    char* ws = (char*)d_ws;
    float*    scal3 = (float*)ws;                       // 3 floats
    unsigned* genp  = (unsigned*)(ws + 256);            // generation word (own line)
    float*    part  = (float*)(ws + 2048);              // 3*512 floats -> [2048, 8192)
    unsigned* arrive= (unsigned*)(ws + 8192);           // 512 uints -> [8192, 10240)
    bf16*     wpk1  = (bf16*)(ws + 10240);              // 18 KiB each
    bf16*     wpk2  = (bf16*)(ws + 28672);
    bf16*     wpk3  = (bf16*)(ws + 47104);              // ends at 65536
    unsigned* wvh   = (unsigned*)(ws + 65536);          // [64 KiB, 64 KiB + 4 MiB)
    char*     A     = ws + 65536 + (size_t)NB*PLANE*4;  // shared region
    // conv-phase mapping of A:
    bf16*  tmp1 = (bf16*)(A);                                  // 64 MiB
    bf16*  tmp2 = (bf16*)(A + (size_t)NB*32*PLANE*2);          // 64 MiB
    float* dv   = (float*)(A + (size_t)NB*32*PLANE*4);         // 4 MiB
    float* dh   = (float*)(A + (size_t)NB*32*PLANE*4 + (size_t)NB*PLANE*4);
    // CG-phase mapping of A (conv temporaries dead by then):
    float* hbuf0 = (float*)A;                                  // Ap-border buffer, parity 0
    float* hbuf1 = (float*)(A + (size_t)NB*PLANE*4);           // parity 1 (r0 at init)

    dim3 cgrid(16, 16, NB);

    // zero control region: scal3/gen [0,2048) + arrive [8192,10240); part needs no init
    hipMemsetAsync(ws, 0, 2048, stream);
    hipMemsetAsync(arrive, 0, 2048, stream);

    // repack the three 32->32 conv weights into MFMA fragment layout
    wrepack3<<<108,256,0,stream>>>(gw2, sw2, vw2, wpk1, wpk2, wpk3);

    // feature branch g = conv(relu(conv(guide)))
    conv3x3_first<3,3,true><<<cgrid,256,0,stream>>>(guide, guide, gw1, gb1, tmp1);
    conv3x3_mfma<false><<<cgrid,256,0,stream>>>(tmp1, wpk1, gb2, tmp2);
    dvdh_cl<false><<<4096,256,0,stream>>>(tmp2, dv, dh);
    // feature branch s = conv(relu(conv(y_bicubic)))
    conv3x3_first<1,1,true><<<cgrid,256,0,stream>>>(ybic, ybic, sw1, sb1, tmp1);
    conv3x3_mfma<false><<<cgrid,256,0,stream>>>(tmp1, wpk2, sb2, tmp2);
    dvdh_cl<true><<<4096,256,0,stream>>>(tmp2, dv, dh);
    aff2_kernel<<<4096,256,0,stream>>>(dv, dh, llam, lmu, wvh, aff_out);
    // variance branch
    conv3x3_first<4,3,true><<<cgrid,256,0,stream>>>(guide, ybic, vw1, vb1, tmp1);
    conv3x3_mfma<true><<<cgrid,256,0,stream>>>(tmp1, wpk3, vb2, tmp2);
    conv3x3_last<<<4096,256,0,stream>>>(tmp2, vw3, vb3, var_out);

    // CG: ONE persistent dispatch, one flag-barrier per iteration
    cg_persist<<<512,256,0,stream>>>(wvh, mask, source, ybic, llam, x_out,
                                     hbuf0, hbuf1, part, arrive, genp, scal3);
}